// Round 2
// baseline (32.614 us; speedup 1.0000x reference)
//
#include <hip/hip_runtime.h>

typedef __bf16 bf16x8 __attribute__((ext_vector_type(8)));
typedef float  f32x4  __attribute__((ext_vector_type(4)));

#define NB 1024
#define NN 128
#define NH 64
#define NOUT 128

__device__ __forceinline__ unsigned short f2b(float f) {
    return __builtin_bit_cast(unsigned short, (__bf16)f);
}

// One block per batch. 256 threads = 4 waves.
// LDS: adj 128x[256B] bf16 swizzled | hT 64x[256B] (feat-major) | S 128x[128B]
// swizzle: byte_in_row ^= (row&7)<<4  (breaks the 256B/128B-stride bank conflict)
// S region is reused: [staging column partials 256x4 f32] -> [S bf16] -> [colsum+svec f32]
__global__ __launch_bounds__(256, 2)
void rsgcn_fused(const int* __restrict__ graph, const float* __restrict__ adj,
                 const float* __restrict__ embed, const float* __restrict__ W1,
                 const float* __restrict__ W2, const float* __restrict__ W3,
                 float* __restrict__ out)
{
    __shared__ __align__(16) char smem[65536];
    char* const adj_s = smem;           // 32768 B
    char* const hT_s  = smem + 32768;   // 16384 B
    char* const S_s   = smem + 49152;   // 16384 B
    float* const part   = (float*)S_s;          // [256][4] staging column partials
    float* const colsum = (float*)S_s;          // [128] epilogue (S dead by then)
    float* const svec   = (float*)(S_s + 512);  // [64]

    const int b    = blockIdx.x;
    const int t    = threadIdx.x;
    const int lane = t & 63;
    const int wv   = t >> 6;

    // ---------------- stage adj: fp32 -> bf16 LDS + fp32 column partials ------
    // thread t owns columns 4*(t&31)..+4 over rows { i*8 + (t>>5) : i in [0,16) }
    const float4* adj4 = (const float4*)(adj + (size_t)b * (NN * NN));
    {
        float p0 = 0.f, p1 = 0.f, p2 = 0.f, p3 = 0.f;
        #pragma unroll
        for (int i = 0; i < 16; ++i) {
            int fi = i * 256 + t;            // float4 index within 128x128 tile
            float4 v = adj4[fi];
            p0 += v.x; p1 += v.y; p2 += v.z; p3 += v.w;
            int row  = fi >> 5;              // 32 float4 per row
            int colb = (fi & 31) * 8;        // byte offset of 4 bf16
            ushort4 u;
            u.x = f2b(v.x); u.y = f2b(v.y); u.z = f2b(v.z); u.w = f2b(v.w);
            *(ushort4*)(adj_s + row * 256 + (colb ^ ((row & 7) << 4))) = u;
        }
        *(float4*)(part + t * 4) = make_float4(p0, p1, p2, p3);
    }

    // ---------------- gather embed[graph[b]] -> hT (feature-major) ------------
    {
        const int j  = t >> 1;
        const int d0 = (t & 1) * 32;
        const int g  = graph[b * NN + j];
        const float4* erow = (const float4*)(embed + g * NH + d0);
        #pragma unroll
        for (int q = 0; q < 8; ++q) {
            float4 v = erow[q];
            int d = d0 + q * 4;
            *(unsigned short*)(hT_s + (d+0)*256 + ((j*2) ^ (((d+0)&7)<<4))) = f2b(v.x);
            *(unsigned short*)(hT_s + (d+1)*256 + ((j*2) ^ (((d+1)&7)<<4))) = f2b(v.y);
            *(unsigned short*)(hT_s + (d+2)*256 + ((j*2) ^ (((d+2)&7)<<4))) = f2b(v.z);
            *(unsigned short*)(hT_s + (d+3)*256 + ((j*2) ^ (((d+3)&7)<<4))) = f2b(v.w);
        }
    }
    __syncthreads();

    // ---------------- reduce column partials -> per-thread colsum register ----
    // colsum[c] = sum_{k<8} part[(c>>2) + 32k][c&3]   (fp32, from fp32 adj)
    float cs = 0.f;
    if (t < 128) {
        #pragma unroll
        for (int k = 0; k < 8; ++k)
            cs += part[(((t >> 2) + 32 * k) << 2) + (t & 3)];
    }
    __syncthreads();   // part (S region) dead; layer-0 may now overwrite S

    // ---------------- layers 1,2: h = relu((adj @ h) @ W^T) -------------------
    #pragma unroll 1
    for (int layer = 0; layer < 2; ++layer) {
        const float* W = (layer == 0) ? W1 : W2;

        // ---- S = adj @ h  (A = adj rows, B = hT rows; 16x16x32 bf16 MFMA) ----
        {
            f32x4 acc[2][4] = {};
            const int r0  = (2 * wv) * 16 + (lane & 15);
            const int r1  = r0 + 16;
            const int kb0 = (lane >> 4) * 16;
            #pragma unroll
            for (int kk = 0; kk < 4; ++kk) {
                int kb = kk * 64 + kb0;
                bf16x8 a0 = *(const bf16x8*)(adj_s + r0*256 + (kb ^ ((r0 & 7) << 4)));
                bf16x8 a1 = *(const bf16x8*)(adj_s + r1*256 + (kb ^ ((r1 & 7) << 4)));
                #pragma unroll
                for (int nt = 0; nt < 4; ++nt) {
                    int rh = nt * 16 + (lane & 15);
                    bf16x8 bb = *(const bf16x8*)(hT_s + rh*256 + (kb ^ ((rh & 7) << 4)));
                    acc[0][nt] = __builtin_amdgcn_mfma_f32_16x16x32_bf16(a0, bb, acc[0][nt], 0, 0, 0);
                    acc[1][nt] = __builtin_amdgcn_mfma_f32_16x16x32_bf16(a1, bb, acc[1][nt], 0, 0, 0);
                }
            }
            // write S[node][d] (row-major, swizzled). D: col=lane&15, row=(lane>>4)*4+i
            #pragma unroll
            for (int m = 0; m < 2; ++m) {
                #pragma unroll
                for (int nt = 0; nt < 4; ++nt) {
                    #pragma unroll
                    for (int i = 0; i < 4; ++i) {
                        int node = (2*wv + m) * 16 + (lane >> 4) * 4 + i;
                        int d    = nt * 16 + (lane & 15);
                        *(unsigned short*)(S_s + node*128 + ((d*2) ^ ((node & 7) << 4))) =
                            f2b(acc[m][nt][i]);
                    }
                }
            }
        }
        __syncthreads();

        // ---- hT = relu(W @ S^T)  (output directly transposed for next layer) -
        {
            // A-fragments from W (global fp32, L2-resident): W[o][d]
            bf16x8 aw[2];
            const int o = wv * 16 + (lane & 15);
            #pragma unroll
            for (int kk = 0; kk < 2; ++kk) {
                int d = kk * 32 + (lane >> 4) * 8;
                const float4* p = (const float4*)(W + o * NH + d);
                float4 v0 = p[0], v1 = p[1];
                bf16x8 a;
                a[0] = (__bf16)v0.x; a[1] = (__bf16)v0.y; a[2] = (__bf16)v0.z; a[3] = (__bf16)v0.w;
                a[4] = (__bf16)v1.x; a[5] = (__bf16)v1.y; a[6] = (__bf16)v1.z; a[7] = (__bf16)v1.w;
                aw[kk] = a;
            }
            f32x4 acc2[8] = {};
            #pragma unroll
            for (int kk = 0; kk < 2; ++kk) {
                int db = kk * 64 + (lane >> 4) * 16;
                #pragma unroll
                for (int nt = 0; nt < 8; ++nt) {
                    int rn = nt * 16 + (lane & 15);
                    bf16x8 bb = *(const bf16x8*)(S_s + rn*128 + (db ^ ((rn & 7) << 4)));
                    acc2[nt] = __builtin_amdgcn_mfma_f32_16x16x32_bf16(aw[kk], bb, acc2[nt], 0, 0, 0);
                }
            }
            __syncthreads();   // all waves done reading S before hT overwrite
            #pragma unroll
            for (int nt = 0; nt < 8; ++nt) {
                #pragma unroll
                for (int i = 0; i < 4; ++i) {
                    int oo   = wv * 16 + (lane >> 4) * 4 + i;
                    int node = nt * 16 + (lane & 15);
                    float v = acc2[nt][i];
                    v = fmaxf(v, 0.0f);                      // relu (layers 1,2 only)
                    *(unsigned short*)(hT_s + oo*256 + ((node*2) ^ ((oo & 7) << 4))) = f2b(v);
                }
            }
        }
        __syncthreads();
    }

    // ---------------- layer 3 collapsed: out = ((1^T adj) h2) W3^T ------------
    // publish register colsum into the (dead) S region
    if (t < 128) colsum[t] = cs;
    __syncthreads();

    // svec[d] = sum_j colsum[j] * h2T[d][j]   (threads 0..63)
    if (t < 64) {
        float s0 = 0.f, s1 = 0.f;
        #pragma unroll
        for (int jj = 0; jj < 16; ++jj) {
            bf16x8 hv = *(const bf16x8*)(hT_s + t*256 + ((jj*16) ^ ((t & 7) << 4)));
            float q0 = 0.f, q1 = 0.f;
            #pragma unroll
            for (int q = 0; q < 4; ++q) {
                q0 += colsum[jj*8 + q]     * (float)hv[q];
                q1 += colsum[jj*8 + 4 + q] * (float)hv[4 + q];
            }
            s0 += q0; s1 += q1;
        }
        svec[t] = s0 + s1;
    }
    __syncthreads();

    // out[b][o] = sum_d W3[o][d] * svec[d]   (threads 0..127, fp32)
    if (t < 128) {
        const float4* wrow = (const float4*)(W3 + t * NH);
        float a0 = 0.f, a1 = 0.f;
        #pragma unroll
        for (int q = 0; q < 16; q += 2) {
            float4 w0 = wrow[q], w1 = wrow[q + 1];
            a0 += w0.x*svec[q*4+0] + w0.y*svec[q*4+1] + w0.z*svec[q*4+2] + w0.w*svec[q*4+3];
            a1 += w1.x*svec[q*4+4] + w1.y*svec[q*4+5] + w1.z*svec[q*4+6] + w1.w*svec[q*4+7];
        }
        out[b * NOUT + t] = a0 + a1;
    }
}

extern "C" void kernel_launch(void* const* d_in, const int* in_sizes, int n_in,
                              void* d_out, int out_size, void* d_ws, size_t ws_size,
                              hipStream_t stream) {
    const int*   graph = (const int*)d_in[0];
    const float* adjp  = (const float*)d_in[1];
    const float* embed = (const float*)d_in[2];
    const float* W1    = (const float*)d_in[3];
    const float* W2    = (const float*)d_in[4];
    const float* W3    = (const float*)d_in[5];
    float* outp = (float*)d_out;

    rsgcn_fused<<<dim3(NB), dim3(256), 0, stream>>>(graph, adjp, embed, W1, W2, W3, outp);
}